// Round 1
// baseline (468.598 us; speedup 1.0000x reference)
//
#include <hip/hip_runtime.h>
#include <hip/hip_bf16.h>

#define V    100000
#define EMB  128
#define REG  7
#define NC   20
#define ML   512
#define BB   64
#define RAD  3
#define ENT  506      // ML - 2*RAD
#define TI   32       // entries per block
#define NBLK 16       // i-chunks per batch row (16*32 = 512 >= 506)

// Kernel 1: noi partial sums.
// noi[b,c] = sum_i max_j ( W_word[ train[b, (t%506)+(t/506)] ][c] *
//                          W_region[ train[b, i+3] ][j*128+c] ),  t = i*7+j
// Each block: one (b, chunk-of-32-i). 256 threads = 4 waves; wave handles
// i_local = w, w+4, ...; lane owns channels {2*lane, 2*lane+1} via float2
// (64 lanes x 8B = one fully-coalesced 512B row segment per j).
__global__ __launch_bounds__(256) void noi_partial_kernel(
    const int*   __restrict__ train,
    const float* __restrict__ Wr,
    const float* __restrict__ Ww,
    float*       __restrict__ partial)
{
    __shared__ int   idx_lds[TI * 8];     // [i_local][0]=region row, [1..7]=word rows
    __shared__ float red[4][EMB];

    const int blk = blockIdx.x;           // 0 .. 64*16-1
    const int b   = blk >> 4;
    const int i0  = (blk & 15) * TI;
    const int tid = threadIdx.x;

    // Precompute the 8 gather indices per entry (256 slots == 256 threads).
    {
        const int il  = tid >> 3;
        const int sub = tid & 7;
        const int i   = i0 + il;
        int v = 0;
        if (i < ENT) {
            if (sub == 0) {
                v = train[b * ML + i + RAD];
            } else {
                const int t = i * REG + (sub - 1);
                const int r = t / ENT;            // const divisor -> magic mul
                const int e = t - r * ENT;
                v = train[b * ML + e + r];
            }
        }
        idx_lds[tid] = v;
    }
    __syncthreads();

    const int w    = tid >> 6;
    const int lane = tid & 63;

    float accx = 0.f, accy = 0.f;
    for (int il = w; il < TI; il += 4) {
        const int i = i0 + il;
        if (i >= ENT) break;                       // wave-uniform
        const int base = il * 8;
        const int ridx = idx_lds[base];
        const float2* Krow = (const float2*)(Wr + (size_t)ridx * (REG * EMB));

        float mx, my;
        {
            const float2* Erow = (const float2*)(Ww + (size_t)idx_lds[base + 1] * EMB);
            const float2 k = Krow[lane];
            const float2 e = Erow[lane];
            mx = k.x * e.x;
            my = k.y * e.y;
        }
        #pragma unroll
        for (int j = 1; j < REG; ++j) {
            const float2* Erow = (const float2*)(Ww + (size_t)idx_lds[base + 1 + j] * EMB);
            const float2 k = Krow[j * 64 + lane];
            const float2 e = Erow[lane];
            mx = fmaxf(mx, k.x * e.x);
            my = fmaxf(my, k.y * e.y);
        }
        accx += mx;
        accy += my;
    }

    red[w][2 * lane]     = accx;
    red[w][2 * lane + 1] = accy;
    __syncthreads();
    if (tid < EMB) {
        const float s = red[0][tid] + red[1][tid] + red[2][tid] + red[3][tid];
        partial[(size_t)blk * EMB + tid] = s;      // every slot written -> no init needed
    }
}

// Kernel 2: one block per batch row. Reduce 16 partials -> noi[128];
// h = relu(noi @ W1 + b1)  (1024); logits = h @ W2 + b2 (20);
// softmax + argmax; write logits | prob | cls(as float).
__global__ __launch_bounds__(256) void mlp_kernel(
    const float* __restrict__ partial,
    const float* __restrict__ W1,
    const float* __restrict__ b1,
    const float* __restrict__ W2,
    const float* __restrict__ b2,
    float*       __restrict__ out)
{
    __shared__ float noi[EMB];
    __shared__ float h[2 * ML];
    __shared__ float lg[NC];

    const int b   = blockIdx.x;
    const int tid = threadIdx.x;

    if (tid < EMB) {
        float s = 0.f;
        #pragma unroll
        for (int k = 0; k < NBLK; ++k)
            s += partial[(size_t)(b * NBLK + k) * EMB + tid];
        noi[tid] = s;
    }
    __syncthreads();

    // h: each thread owns 4 columns (tid, tid+256, tid+512, tid+768)
    float h0 = b1[tid], h1 = b1[tid + 256], h2 = b1[tid + 512], h3 = b1[tid + 768];
    for (int k = 0; k < EMB; ++k) {
        const float nk = noi[k];
        const float* row = W1 + k * (2 * ML);
        h0 = fmaf(nk, row[tid],       h0);
        h1 = fmaf(nk, row[tid + 256], h1);
        h2 = fmaf(nk, row[tid + 512], h2);
        h3 = fmaf(nk, row[tid + 768], h3);
    }
    h[tid]       = fmaxf(h0, 0.f);
    h[tid + 256] = fmaxf(h1, 0.f);
    h[tid + 512] = fmaxf(h2, 0.f);
    h[tid + 768] = fmaxf(h3, 0.f);
    __syncthreads();

    // logits: wave w handles classes c = w, w+4, ...; lanes split k.
    const int w    = tid >> 6;
    const int lane = tid & 63;
    for (int c = w; c < NC; c += 4) {
        float p = 0.f;
        #pragma unroll 4
        for (int k = lane; k < 2 * ML; k += 64)
            p = fmaf(h[k], W2[k * NC + c], p);
        for (int off = 32; off; off >>= 1)
            p += __shfl_down(p, off);
        if (lane == 0) lg[c] = p + b2[c];
    }
    __syncthreads();

    if (tid == 0) {
        float mx = lg[0];
        for (int c = 1; c < NC; ++c) mx = fmaxf(mx, lg[c]);
        float pr[NC];
        float s = 0.f;
        for (int c = 0; c < NC; ++c) { pr[c] = expf(lg[c] - mx); s += pr[c]; }
        const float inv = 1.f / s;
        int am = 0; float best = lg[0];
        for (int c = 1; c < NC; ++c) if (lg[c] > best) { best = lg[c]; am = c; }
        for (int c = 0; c < NC; ++c) {
            out[b * NC + c]           = lg[c];           // logits
            out[BB * NC + b * NC + c] = pr[c] * inv;     // prob
        }
        out[2 * BB * NC + b] = (float)am;                // cls (as float)
    }
}

extern "C" void kernel_launch(void* const* d_in, const int* in_sizes, int n_in,
                              void* d_out, int out_size, void* d_ws, size_t ws_size,
                              hipStream_t stream) {
    const int*   train = (const int*)  d_in[0];
    const float* Wr    = (const float*)d_in[1];
    const float* Ww    = (const float*)d_in[2];
    const float* W1    = (const float*)d_in[3];
    const float* b1    = (const float*)d_in[4];
    const float* W2    = (const float*)d_in[5];
    const float* b2    = (const float*)d_in[6];
    float* out     = (float*)d_out;
    float* partial = (float*)d_ws;     // 64*16*128*4 = 512 KB

    hipLaunchKernelGGL(noi_partial_kernel, dim3(BB * NBLK), dim3(256), 0, stream,
                       train, Wr, Ww, partial);
    hipLaunchKernelGGL(mlp_kernel, dim3(BB), dim3(256), 0, stream,
                       partial, W1, b1, W2, b2, out);
}